// Round 5
// baseline (145.928 us; speedup 1.0000x reference)
//
#include <hip/hip_runtime.h>
#include <hip/hip_bf16.h>
#include <stdint.h>

typedef __bf16 bf16x8 __attribute__((ext_vector_type(8)));
typedef float f32x4 __attribute__((ext_vector_type(4)));

#define MAXD 40
#define ND   81
#define CSZ  256
#define HSZ  128
#define WSZ  416
#define HW   (HSZ * WSZ)
#define RST  40          // bf16 per LDS row: 32 data + 8 pad (80 B)
#define NCHUNK 8
#define NTILE 156        // 26 w-rows x 6 u-tiles

// LDS-only drain barrier: global loads stay in flight across it (T4).
static __device__ __forceinline__ void lds_barrier() {
    asm volatile("s_waitcnt lgkmcnt(0)" ::: "memory");
    __builtin_amdgcn_s_barrier();
    __builtin_amdgcn_sched_barrier(0);
}

__global__ __launch_bounds__(1024, 4)
void corr_mfma_kernel(const float* __restrict__ left,
                      const float* __restrict__ right,
                      float* __restrict__ out) {
    __shared__ __align__(16) __bf16 Lt[WSZ * RST];   // [w][c]    33280 B
    __shared__ __align__(16) __bf16 Rt[512 * RST];   // [u+40][c] 40960 B

    const int t   = threadIdx.x;
    const int wv  = t >> 6;      // 0..15
    const int l   = t & 63;
    const int l15 = l & 15;
    const int l4  = l >> 4;      // 0..3
    const int b   = blockIdx.x >> 7;
    const int h   = blockIdx.x & 127;

    // staging: sc = channel (0..31), swq = w lane (0..31, stride-1 rows)
    const int sc  = t >> 5;
    const int swq = t & 31;

    const size_t slab = ((size_t)b * CSZ) * HW + (size_t)h * WSZ;
    const float* Lp = left  + slab + (size_t)sc * HW;
    const float* Rp = right + slab + (size_t)sc * HW;

    f32x4 acc[10];
    #pragma unroll
    for (int s = 0; s < 10; ++s) acc[s] = (f32x4)0.0f;

    // zero the permanent R halo rows (0..31 and 480..511) once
    {
        const int zr = t >> 5;       // 0..31
        const int zc = t & 31;
        Rt[zr * RST + zc]           = (__bf16)0.0f;
        Rt[(zr + 480) * RST + zc]   = (__bf16)0.0f;
    }

    float lv[13], rv[14];

    // ---- prologue: load + stage chunk 0 ----
    #pragma unroll
    for (int i = 0; i < 13; ++i)
        lv[i] = Lp[swq + 32 * i];
    #pragma unroll
    for (int i = 0; i < 14; ++i) {
        const int u = swq + 32 * (i + 1) - MAXD;
        rv[i] = ((unsigned)u < (unsigned)WSZ) ? Rp[u] : 0.0f;
    }
    // sync the halo zero-writes before first tile writes complete view
    #pragma unroll
    for (int i = 0; i < 13; ++i)
        Lt[(swq + 32 * i) * RST + sc] = (__bf16)lv[i];
    #pragma unroll
    for (int i = 0; i < 14; ++i)
        Rt[(swq + 32 * (i + 1)) * RST + sc] = (__bf16)rv[i];

    lds_barrier();   // tile 0 visible

    for (int ck = 0; ck < NCHUNK; ++ck) {
        const bool more = (ck + 1 < NCHUNK);

        // ---- A) issue next-chunk loads early (in flight across MFMA + barriers) ----
        if (more) {
            const size_t cof = (size_t)(ck + 1) * 32 * HW;
            #pragma unroll
            for (int i = 0; i < 13; ++i)
                lv[i] = Lp[cof + swq + 32 * i];
            #pragma unroll
            for (int i = 0; i < 14; ++i) {
                const int u = swq + 32 * (i + 1) - MAXD;
                rv[i] = ((unsigned)u < (unsigned)WSZ) ? Rp[cof + u] : 0.0f;
            }
        }

        // ---- B) banded MFMA: 10 tiles per wave, tile id tau = wv + 16s ----
        #pragma unroll
        for (int s = 0; s < 10; ++s) {
            const int tau = wv + 16 * s;
            if (tau < NTILE) {
                const int row = tau / 6;
                const int j   = tau - 6 * row;
                const bf16x8 a  = *(const bf16x8*)&Lt[(16 * row + l15) * RST + 8 * l4];
                const bf16x8 bb = *(const bf16x8*)&Rt[(16 * (row + j) + l15) * RST + 8 * l4];
                acc[s] = __builtin_amdgcn_mfma_f32_16x16x32_bf16(a, bb, acc[s], 0, 0, 0);
            }
        }

        if (more) {
            lds_barrier();   // everyone done reading tile ck

            // ---- C) cvt + LDS write of tile ck+1 ----
            #pragma unroll
            for (int i = 0; i < 13; ++i)
                Lt[(swq + 32 * i) * RST + sc] = (__bf16)lv[i];
            #pragma unroll
            for (int i = 0; i < 14; ++i)
                Rt[(swq + 32 * (i + 1)) * RST + sc] = (__bf16)rv[i];

            lds_barrier();   // tile ck+1 visible
        }
    }

    // ---- epilogue: C row m = 4*l4 + r (w off), col n = l15 (u off); d = 16j + n - m ----
    const float scale = 1.0f / 256.0f;
    #pragma unroll
    for (int s = 0; s < 10; ++s) {
        const int tau = wv + 16 * s;
        if (tau < NTILE) {
            const int row = tau / 6;
            const int j   = tau - 6 * row;
            const int wbase = 16 * row;
            #pragma unroll
            for (int r = 0; r < 4; ++r) {
                const int m = 4 * l4 + r;
                const int d = 16 * j + l15 - m;
                if ((unsigned)d < (unsigned)ND) {
                    out[(((size_t)b * ND + d) * HSZ + h) * WSZ + (wbase + m)] = acc[s][r] * scale;
                }
            }
        }
    }
}

extern "C" void kernel_launch(void* const* d_in, const int* in_sizes, int n_in,
                              void* d_out, int out_size, void* d_ws, size_t ws_size,
                              hipStream_t stream) {
    const float* left  = (const float*)d_in[0];
    const float* right = (const float*)d_in[1];
    float* out = (float*)d_out;
    (void)in_sizes; (void)n_in; (void)out_size; (void)d_ws; (void)ws_size;
    corr_mfma_kernel<<<dim3(4 * 128), dim3(1024), 0, stream>>>(left, right, out);
}